// Round 10
// baseline (116.941 us; speedup 1.0000x reference)
//
#include <hip/hip_runtime.h>
#include <hip/hip_bf16.h>

typedef __attribute__((ext_vector_type(8))) short short8;
typedef __attribute__((ext_vector_type(4))) float f32x4;

namespace {
constexpr int Nc  = 2048;   // N
constexpr int NXc = 4096;   // 2N
constexpr int Pc  = 64;
constexpr int Mc  = 4;
constexpr int Dc  = 256;
constexpr int BH  = 16;
constexpr float LOG2E = 1.4426950408889634f;
}

__device__ inline float fexp2(float x) {
#if __has_builtin(__builtin_amdgcn_exp2f)
  return __builtin_amdgcn_exp2f(x);
#else
  return exp2f(x);
#endif
}

__device__ inline unsigned int bfpack(float a, float b) {
  union { __hip_bfloat162 h; unsigned int u; } cv;
  cv.h = __float22bfloat162_rn(make_float2(a, b));
  return cv.u;
}

// Gather pre-pass: Wb[bh][m*256+d][64] = bf16( LOG2E * X[bh][SK[b,m,d]][:] )
__global__ __launch_bounds__(256) void prepass_kernel(
    const float* __restrict__ Q, const float* __restrict__ K,
    const int* __restrict__ SK, __hip_bfloat16* __restrict__ Wb)
{
  const int t  = blockIdx.x * 256 + threadIdx.x;
  const int q  = t & 7;
  const int r  = t >> 3;            // 0..16383
  const int bh = r >> 10;
  const int md = r & 1023;
  const int b  = bh >> 3;
  const int idx = SK[b * (Mc * Dc) + md];
  const float* src = (idx < Nc) ? (Q + ((size_t)bh * Nc + idx) * Pc)
                                : (K + ((size_t)bh * Nc + (idx - Nc)) * Pc);
  const f32x4* s4 = (const f32x4*)(src + q * 8);
  f32x4 f0 = s4[0], f1 = s4[1];
  uint4 u;
  u.x = bfpack(f0.x * LOG2E, f0.y * LOG2E);
  u.y = bfpack(f0.z * LOG2E, f0.w * LOG2E);
  u.z = bfpack(f1.x * LOG2E, f1.y * LOG2E);
  u.w = bfpack(f1.z * LOG2E, f1.w * LOG2E);
  *(uint4*)(Wb + (size_t)r * Pc + q * 8) = u;
}

// Main kernel, occupancy-first. Block = (nch, dq, bh): 4 waves, 32 d x 256 n.
//
// Round-9 post-mortem: latency-bound (r2 counters: VALUBusy 15%, occupancy
// 24%, HBM 1.95 TB/s; per-SIMD issue budget only ~5 us vs 36 us runtime).
// This version is built for VGPR <= 85 -> __launch_bounds__(256,6) ->
// 24 waves/CU (1.5x round 9), trading 2x LDS re-reads (cheap, ~1.3 us/SIMD)
// for register thrift:
//  - 32-d slice (dt in {0,1}), LDS tile 16 KB (4m x 32d x 64k bf16, XOR-
//    swizzled byte ^= (row&7)<<4 -> conflict-free ds_read_b128).
//  - wave owns 4 n-tiles processed in 2 PAIRS: per pair b-frags 16 + acc 16
//    + a 8 + c 4 + sg 4 + addr ~12 + cvt transient -> ~64-80 peak VGPR.
//    No cross-pair X preload (register-rename spill hazard); exposed X
//    latency is L2/L3-hot and covered by 6 waves/SIMD.
//  - pair-0 X loads issued BEFORE the single barrier (hide under staging).
//  - nontemporal f32x4 stores; block writes 128 B contiguous per row
//    (= exactly one cache line).
//
// Grid 128 x 16 = 2048 blocks; decode groups all 8 dq-siblings of one nch
// onto one XCD (hw round-robins blockIdx across XCDs: xcd = bx&7).
//
// MFMA: A = W rows (d), B = X rows (n) => C: row = d (q*4+reg), col = n (brow).
__global__ __launch_bounds__(256, 6) void sketch_main(
    const float* __restrict__ Q, const float* __restrict__ K,
    const __hip_bfloat16* __restrict__ Wb,
    const float* __restrict__ SGN, float* __restrict__ OUT)
{
  __shared__ __hip_bfloat16 Ws[Mc * 32 * Pc];   // 16 KB

  const int t    = threadIdx.x;
  const int lane = t & 63;
  const int wv   = t >> 6;
  const int brow = lane & 15;
  const int q    = lane >> 4;
  const int bh   = blockIdx.y;

  // XCD-grouping decode: 8 dq-siblings of one nch on one XCD
  const int bx  = blockIdx.x;            // 0..127
  const int xcd = bx & 7;
  const int rr  = bx >> 3;               // 0..15
  const int nch = xcd * 2 + (rr >> 3);   // 0..15
  const int dq  = rr & 7;                // 0..7
  const int n0  = nch * 256;
  const int d0  = dq * 32;

  char* wsb = (char*)Ws;

  // ---- Stage W slice: Wb rows m*256 + [d0, d0+32) -> swizzled LDS.
  // 4 threads per 128B row, 2 passes for the 128 rows. Coalesced from L2.
  {
    const int qt = t & 3;                // 32B quarter of the row
    const int r4 = t >> 2;               // 0..63
    #pragma unroll
    for (int p = 0; p < 2; ++p) {
      const int row = p * 64 + r4;       // 0..127 = m*32 + dl
      const int m  = row >> 5;
      const int dl = row & 31;
      const __hip_bfloat16* wsrc =
          Wb + ((size_t)bh * (Mc * Dc) + m * Dc + d0 + dl) * Pc + qt * 16;
      uint4 wa = *(const uint4*)(wsrc);
      uint4 wb = *(const uint4*)(wsrc + 8);
      char* rp = wsb + row * 128;
      const int sw = (row & 7) << 4;
      *(uint4*)(rp + ((qt * 32) ^ sw))      = wa;
      *(uint4*)(rp + ((qt * 32 + 16) ^ sw)) = wb;
    }
  }

  // ---- Issue pair-0 X loads BEFORE the barrier (stay in flight across it)
  const float* xrw = ((n0 < Nc) ? (Q + ((size_t)bh * Nc + n0) * Pc)
                                : (K + ((size_t)bh * Nc + (n0 - Nc)) * Pc))
                     + (size_t)(wv * 64 + brow) * Pc + q * 8;
  f32x4 xv[8];
  #pragma unroll
  for (int tt = 0; tt < 2; ++tt) {
    const float* xp = xrw + (size_t)tt * 16 * Pc;
    xv[tt * 4 + 0] = *(const f32x4*)(xp);
    xv[tt * 4 + 1] = *(const f32x4*)(xp + 4);
    xv[tt * 4 + 2] = *(const f32x4*)(xp + 32);
    xv[tt * 4 + 3] = *(const f32x4*)(xp + 36);
  }

  __syncthreads();   // the only barrier

  const int swr = (brow & 7) << 4;   // read row = m*32+dt*16+brow; &7 == brow&7
  float* obase = OUT + ((size_t)bh * NXc + n0 + wv * 64 + brow) * Dc + d0 + q * 4;

  #pragma unroll
  for (int pr = 0; pr < 2; ++pr) {
    // load pair's X (pair 0 already in flight; pair 1 loads here, L2/L3-hot)
    if (pr == 1) {
      #pragma unroll
      for (int tt = 0; tt < 2; ++tt) {
        const float* xp = xrw + (size_t)(2 + tt) * 16 * Pc;
        xv[tt * 4 + 0] = *(const f32x4*)(xp);
        xv[tt * 4 + 1] = *(const f32x4*)(xp + 4);
        xv[tt * 4 + 2] = *(const f32x4*)(xp + 32);
        xv[tt * 4 + 3] = *(const f32x4*)(xp + 36);
      }
    }
    // convert to bf16 B-fragments (16 VGPR)
    short8 b0[2], b1[2];
    #pragma unroll
    for (int tt = 0; tt < 2; ++tt) {
      union { short8 s; uint4 u; } c0, c1;
      f32x4 x0 = xv[tt * 4 + 0], x1 = xv[tt * 4 + 1];
      f32x4 x2 = xv[tt * 4 + 2], x3 = xv[tt * 4 + 3];
      c0.u.x = bfpack(x0.x, x0.y); c0.u.y = bfpack(x0.z, x0.w);
      c0.u.z = bfpack(x1.x, x1.y); c0.u.w = bfpack(x1.z, x1.w);
      c1.u.x = bfpack(x2.x, x2.y); c1.u.y = bfpack(x2.z, x2.w);
      c1.u.z = bfpack(x3.x, x3.y); c1.u.w = bfpack(x3.z, x3.w);
      b0[tt] = c0.s; b1[tt] = c1.s;
    }

    f32x4 acc[2][2];   // [tt][dt]
    #pragma unroll
    for (int tt = 0; tt < 2; ++tt)
      #pragma unroll
      for (int dt = 0; dt < 2; ++dt) acc[tt][dt] = (f32x4){0.f, 0.f, 0.f, 0.f};

    #pragma unroll
    for (int dt = 0; dt < 2; ++dt) {
      #pragma unroll
      for (int m = 0; m < 4; ++m) {
        const char* ap = wsb + (m * 32 + dt * 16 + brow) * 128;
        short8 a0 = *(const short8*)(ap + ((q * 16) ^ swr));
        short8 a1 = *(const short8*)(ap + ((64 + q * 16) ^ swr));
        const f32x4 sg = *(const f32x4*)(SGN + m * Dc + d0 + dt * 16 + q * 4);
        #pragma unroll
        for (int tt = 0; tt < 2; ++tt) {
          f32x4 c = {0.f, 0.f, 0.f, 0.f};
          c = __builtin_amdgcn_mfma_f32_16x16x32_bf16(a0, b0[tt], c, 0, 0, 0);
          c = __builtin_amdgcn_mfma_f32_16x16x32_bf16(a1, b1[tt], c, 0, 0, 0);
          acc[tt][dt].x = fmaf(sg.x, fexp2(c.x), acc[tt][dt].x);
          acc[tt][dt].y = fmaf(sg.y, fexp2(c.y), acc[tt][dt].y);
          acc[tt][dt].z = fmaf(sg.z, fexp2(c.z), acc[tt][dt].z);
          acc[tt][dt].w = fmaf(sg.w, fexp2(c.w), acc[tt][dt].w);
        }
      }
    }

    // stores: n = n0 + (pr*2+tt)*16 + wv*64 + brow, d = d0 + dt*16 + q*4+reg
    #pragma unroll
    for (int tt = 0; tt < 2; ++tt) {
      #pragma unroll
      for (int dt = 0; dt < 2; ++dt) {
        __builtin_nontemporal_store(
            acc[tt][dt],
            (f32x4*)(obase + (size_t)(pr * 2 + tt) * 16 * Dc + dt * 16));
      }
    }
  }
}

extern "C" void kernel_launch(void* const* d_in, const int* in_sizes, int n_in,
                              void* d_out, int out_size, void* d_ws, size_t ws_size,
                              hipStream_t stream) {
  (void)in_sizes; (void)n_in; (void)out_size; (void)ws_size;
  const float* Q   = (const float*)d_in[0];
  const float* K   = (const float*)d_in[1];
  const int*   SK  = (const int*)d_in[2];
  const float* SGN = (const float*)d_in[3];
  float* OUT = (float*)d_out;

  __hip_bfloat16* Wb = (__hip_bfloat16*)d_ws;  // 2 MiB

  prepass_kernel<<<dim3(512), dim3(256), 0, stream>>>(Q, K, SK, Wb);
  sketch_main<<<dim3(128, BH), dim3(256), 0, stream>>>(Q, K, Wb, SGN, OUT);
}